// Round 2
// baseline (1134.159 us; speedup 1.0000x reference)
//
#include <hip/hip_runtime.h>
#include <math.h>

// ---------------- problem constants ----------------
#define NTOK   1024      // B*T
#define EXP    16
#define TOPK   4
#define DMODEL 2048
#define DFFN   3584
#define HT_TILES 56      // DFFN/64
#define CT_TILES 32      // DMODEL/64
#define NSLOT  4096      // NTOK*TOPK, always exactly filled

typedef __attribute__((ext_vector_type(8))) short bf16x8;
typedef __attribute__((ext_vector_type(4))) float f32x4;

// ---------------- workspace layout (bytes) ----------------
#define O_COUNTS 0
#define O_BASE   256
#define O_CURSOR 512
#define O_TOPI   4096
#define O_TOPW   (O_TOPI + 16384)
#define O_TOK    (O_TOPW + 16384)
#define O_WGT    (O_TOK + 16384)
#define O_SLOTNK (O_WGT + 16384)
#define O_XG     (O_SLOTNK + 16384)                 // bf16 [4096][2048] = 16.78 MB
#define O_HBUF   (O_XG + (size_t)NSLOT*DMODEL*2)    // bf16 [4096][3584] = 29.36 MB
// ypart aliases xg: xg is dead after k_upgate, ypart born in k_down.

__device__ __forceinline__ unsigned short f2b_rne(float f) {
  unsigned u = __builtin_bit_cast(unsigned, f);
  u += 0x7FFFu + ((u >> 16) & 1u);
  return (unsigned short)(u >> 16);
}
__device__ __forceinline__ float b2f(unsigned short h) {
  unsigned u = ((unsigned)h) << 16;
  return __builtin_bit_cast(float, u);
}

// async 16B global->LDS (wave-uniform LDS base + lane*16; per-lane global src)
__device__ __forceinline__ void gl16(const unsigned short* g, unsigned short* l) {
  __builtin_amdgcn_global_load_lds(
      (const __attribute__((address_space(1))) void*)g,
      (__attribute__((address_space(3))) void*)l, 16, 0, 0);
}

// store 4 fp32 -> 4 bf16 into LDS tile (row stride 64 bf16), XOR-swizzled at 16B granularity
__device__ __forceinline__ void st_bf16x4(unsigned short* lds, int row, int c4, float4 v) {
  unsigned long long p = (unsigned long long)f2b_rne(v.x)
    | ((unsigned long long)f2b_rne(v.y) << 16)
    | ((unsigned long long)f2b_rne(v.z) << 32)
    | ((unsigned long long)f2b_rne(v.w) << 48);
  *(unsigned long long*)(lds + row*64 + (((c4 >> 1) ^ (row & 7)) * 8) + (c4 & 1) * 4) = p;
}
// read one MFMA fragment (8 bf16 = 16B) from swizzled LDS tile
__device__ __forceinline__ bf16x8 ld_frag(const unsigned short* lds, int row, int chunk) {
  return *(const bf16x8*)(lds + row*64 + ((chunk ^ (row & 7)) * 8));
}

// ---------------- K0: zero counters ----------------
__global__ void k_zero(int* counts, int* cursor) {
  int t = threadIdx.x;
  if (t < EXP) { counts[t] = 0; cursor[t] = 0; }
}

// ---------------- K1: router (fp32, exact top-4 like lax.top_k) ----------------
__global__ void k_gate(const float* __restrict__ x, const float* __restrict__ gi,
                       int* __restrict__ topi, float* __restrict__ topw,
                       int* __restrict__ counts) {
  int n = blockIdx.x;
  int lane = threadIdx.x & 63, wave = threadIdx.x >> 6;
  __shared__ float lg[EXP];
  const float4* xr = (const float4*)(x + (size_t)n * DMODEL);
  #pragma unroll
  for (int i = 0; i < 4; ++i) {
    int e = wave * 4 + i;
    const float4* gr = (const float4*)(gi + (size_t)e * DMODEL);
    float s = 0.f;
    #pragma unroll
    for (int j = 0; j < 8; ++j) {
      float4 a = xr[j*64 + lane];
      float4 b = gr[j*64 + lane];
      s += a.x*b.x + a.y*b.y + a.z*b.z + a.w*b.w;
    }
    #pragma unroll
    for (int off = 32; off; off >>= 1) s += __shfl_xor(s, off);
    if (lane == 0) lg[e] = s;
  }
  __syncthreads();
  if (threadIdx.x == 0) {
    float v[EXP];
    #pragma unroll
    for (int j = 0; j < EXP; ++j) v[j] = lg[j];
    int bi[TOPK]; float bv[TOPK];
    #pragma unroll
    for (int k = 0; k < TOPK; ++k) {
      float best = -3.4e38f; int bidx = 0;
      for (int j = 0; j < EXP; ++j) if (v[j] > best) { best = v[j]; bidx = j; }
      bv[k] = best; bi[k] = bidx; v[bidx] = -3.4e38f;
    }
    float m = bv[0], ss = 0.f, w[TOPK];
    #pragma unroll
    for (int k = 0; k < TOPK; ++k) { w[k] = expf(bv[k] - m); ss += w[k]; }
    #pragma unroll
    for (int k = 0; k < TOPK; ++k) {
      topi[n*TOPK + k] = bi[k];
      topw[n*TOPK + k] = w[k] / ss;
      atomicAdd(&counts[bi[k]], 1);
    }
  }
}

// ---------------- K2: exclusive prefix over 16 counts ----------------
__global__ void k_prefix(const int* __restrict__ counts, int* __restrict__ basep) {
  if (threadIdx.x == 0) {
    int acc = 0;
    for (int e = 0; e < EXP; ++e) { basep[e] = acc; acc += counts[e]; }
  }
}

// ---------------- K3: scatter assignments into expert-sorted slots ----------------
__global__ void k_scatter(const int* __restrict__ topi, const float* __restrict__ topw,
                          const int* __restrict__ basep, int* __restrict__ cursor,
                          int* __restrict__ tok, float* __restrict__ wgt,
                          int* __restrict__ slotnk) {
  int n = blockIdx.x * blockDim.x + threadIdx.x;
  if (n >= NTOK) return;
  #pragma unroll
  for (int k = 0; k < TOPK; ++k) {
    int e = topi[n*TOPK + k];
    int pos = atomicAdd(&cursor[e], 1);
    int slot = basep[e] + pos;
    tok[slot] = n;
    wgt[slot] = topw[n*TOPK + k];
    slotnk[n*TOPK + k] = slot;
  }
}

// ---------------- K3b: gather x rows into expert-sorted bf16 buffer ----------------
// xg[slot][c] = bf16(x[tok[slot]][c]), linear layout (swizzle applied at stage time
// via per-lane global_load_lds source addresses).
__global__ void k_gather(const float* __restrict__ x, const int* __restrict__ tok,
                         unsigned short* __restrict__ xg) {
  int slot = blockIdx.x;
  int t = tok[slot];
  int c0 = threadIdx.x * 8;
  const float* src = x + (size_t)t * DMODEL + c0;
  float4 a = *(const float4*)(src);
  float4 b = *(const float4*)(src + 4);
  unsigned u0 = (unsigned)f2b_rne(a.x) | ((unsigned)f2b_rne(a.y) << 16);
  unsigned u1 = (unsigned)f2b_rne(a.z) | ((unsigned)f2b_rne(a.w) << 16);
  unsigned u2 = (unsigned)f2b_rne(b.x) | ((unsigned)f2b_rne(b.y) << 16);
  unsigned u3 = (unsigned)f2b_rne(b.z) | ((unsigned)f2b_rne(b.w) << 16);
  uint4 o = {u0, u1, u2, u3};
  *(uint4*)(xg + (size_t)slot * DMODEL + c0) = o;
}

// ---------------- K4: fused up+gate GEMM + SiLU, 2-phase pipelined ----------------
// grid: e*HT_TILES + ht ; block 256 (4 waves, 2M x 2H wave grid), M-chunks of 128.
__global__ __launch_bounds__(256) void k_upgate(
    const unsigned short* __restrict__ xg,
    const float* __restrict__ Wu, const float* __restrict__ Wg,
    const int* __restrict__ counts, const int* __restrict__ basep,
    const float* __restrict__ wgt,
    unsigned short* __restrict__ hbuf) {
  int e  = blockIdx.x / HT_TILES;
  int ht = blockIdx.x % HT_TILES;
  int n_e = counts[e];
  if (n_e == 0) return;
  int base_e = basep[e];
  int nm = (n_e + 127) >> 7;

  __shared__ unsigned short xs[2][128*64];
  __shared__ unsigned short us[2][64*64];
  __shared__ unsigned short gs[2][64*64];
  __shared__ float swgt[128];

  int tid = threadIdx.x;
  int lane = tid & 63, wave = tid >> 6;
  int wm = wave >> 1, wh = wave & 1;
  const float* wu_base = Wu + ((size_t)e * DFFN + (size_t)ht * 64) * DMODEL;
  const float* wg_base = Wg + ((size_t)e * DFFN + (size_t)ht * 64) * DMODEL;

  // per-lane x-stage geometry (instr i: 8 rows per wave-instr)
  int xrow_lo = lane >> 3;          // 0..7 within the 8-row group
  int xpc     = lane & 7;           // physical 16B chunk within row

  float4 wur[4], wgr[4];

  for (int mch = 0; mch < nm; ++mch) {
    __syncthreads();
    if (tid < 128) {
      int r = mch*128 + tid;
      swgt[tid] = (r < n_e) ? wgt[base_e + r] : 0.f;
    }

    // ---- prologue: stage kc=0 into buffer 0 ----
    #pragma unroll
    for (int i = 0; i < 4; ++i) {
      int row = (i*4 + wave)*8 + xrow_lo;
      int slotr = base_e + mch*128 + row;
      if (slotr > NSLOT-1) slotr = NSLOT-1;
      const unsigned short* src = xg + (size_t)slotr*DMODEL + ((xpc ^ (row & 7)) * 8);
      gl16(src, &xs[0][(i*4 + wave)*8*64]);
    }
    #pragma unroll
    for (int i = 0; i < 4; ++i) {
      int idx = i*256 + tid, row = idx >> 4, c4 = idx & 15;
      wur[i] = *(const float4*)(wu_base + (size_t)row*DMODEL + c4*4);
      wgr[i] = *(const float4*)(wg_base + (size_t)row*DMODEL + c4*4);
    }
    #pragma unroll
    for (int i = 0; i < 4; ++i) {
      int idx = i*256 + tid, row = idx >> 4, c4 = idx & 15;
      st_bf16x4(us[0], row, c4, wur[i]);
      st_bf16x4(gs[0], row, c4, wgr[i]);
    }
    __syncthreads();   // drains vmcnt (gload_lds) + lgkm (ds_write)

    f32x4 ua[4][2], ga[4][2];
    #pragma unroll
    for (int t = 0; t < 4; ++t)
      #pragma unroll
      for (int j = 0; j < 2; ++j) {
        f32x4 z = {0.f,0.f,0.f,0.f};
        ua[t][j] = z; ga[t][j] = z;
      }

    for (int kc = 0; kc < DMODEL/64; ++kc) {
      const int cur = kc & 1, nxt = cur ^ 1;
      const bool pf = (kc + 1 < DMODEL/64);
      // ---- issue next-tile loads first (overlap with compute) ----
      if (pf) {
        #pragma unroll
        for (int i = 0; i < 4; ++i) {
          int row = (i*4 + wave)*8 + xrow_lo;
          int slotr = base_e + mch*128 + row;
          if (slotr > NSLOT-1) slotr = NSLOT-1;
          const unsigned short* src = xg + (size_t)slotr*DMODEL + (kc+1)*64
                                         + ((xpc ^ (row & 7)) * 8);
          gl16(src, &xs[nxt][(i*4 + wave)*8*64]);
        }
        #pragma unroll
        for (int i = 0; i < 4; ++i) {
          int idx = i*256 + tid, row = idx >> 4, c4 = idx & 15;
          wur[i] = *(const float4*)(wu_base + (size_t)row*DMODEL + (kc+1)*64 + c4*4);
          wgr[i] = *(const float4*)(wg_base + (size_t)row*DMODEL + (kc+1)*64 + c4*4);
        }
      }
      // ---- compute current tile ----
      #pragma unroll
      for (int kk = 0; kk < 2; ++kk) {
        int chunk = kk*4 + (lane >> 4);
        bf16x8 a[4], bu[2], bg[2];
        #pragma unroll
        for (int t = 0; t < 4; ++t) a[t] = ld_frag(xs[cur], wm*64 + t*16 + (lane & 15), chunk);
        #pragma unroll
        for (int j = 0; j < 2; ++j) {
          bu[j] = ld_frag(us[cur], wh*32 + j*16 + (lane & 15), chunk);
          bg[j] = ld_frag(gs[cur], wh*32 + j*16 + (lane & 15), chunk);
        }
        #pragma unroll
        for (int t = 0; t < 4; ++t)
          #pragma unroll
          for (int j = 0; j < 2; ++j) {
            ua[t][j] = __builtin_amdgcn_mfma_f32_16x16x32_bf16(a[t], bu[j], ua[t][j], 0, 0, 0);
            ga[t][j] = __builtin_amdgcn_mfma_f32_16x16x32_bf16(a[t], bg[j], ga[t][j], 0, 0, 0);
          }
      }
      // ---- convert + write next weight tiles (write-late) ----
      if (pf) {
        #pragma unroll
        for (int i = 0; i < 4; ++i) {
          int idx = i*256 + tid, row = idx >> 4, c4 = idx & 15;
          st_bf16x4(us[nxt], row, c4, wur[i]);
          st_bf16x4(gs[nxt], row, c4, wgr[i]);
        }
      }
      __syncthreads();
    }

    // ---- epilogue: h = silu(g)*u * gate_weight -> bf16 hbuf ----
    #pragma unroll
    for (int t = 0; t < 4; ++t)
      #pragma unroll
      for (int j = 0; j < 2; ++j)
        #pragma unroll
        for (int r = 0; r < 4; ++r) {
          int ml = wm*64 + t*16 + (lane >> 4)*4 + r;
          if (mch*128 + ml < n_e) {
            float u = ua[t][j][r], g = ga[t][j][r];
            float hv = u * (g / (1.f + expf(-g))) * swgt[ml];
            int slot = base_e + mch*128 + ml;
            hbuf[(size_t)slot*DFFN + ht*64 + wh*32 + j*16 + (lane & 15)] = f2b_rne(hv);
          }
        }
  }
}

// ---------------- K5: down-proj GEMM -> per-slot partials, 2-phase pipelined ------
__global__ __launch_bounds__(256) void k_down(
    const unsigned short* __restrict__ hbuf, const float* __restrict__ Wd,
    const int* __restrict__ counts, const int* __restrict__ basep,
    unsigned short* __restrict__ ypart) {
  int e  = blockIdx.x / CT_TILES;
  int ct = blockIdx.x % CT_TILES;
  int n_e = counts[e];
  if (n_e == 0) return;
  int base_e = basep[e];
  int nm = (n_e + 127) >> 7;

  __shared__ unsigned short hs[2][128*64];
  __shared__ unsigned short dwS[2][64*64];

  int tid = threadIdx.x;
  int lane = tid & 63, wave = tid >> 6;
  int wm = wave >> 1, wh = wave & 1;
  const float* wd_base = Wd + ((size_t)e * DMODEL + (size_t)ct * 64) * DFFN;

  int xrow_lo = lane >> 3;
  int xpc     = lane & 7;

  float4 wdr[4];

  for (int mch = 0; mch < nm; ++mch) {
    __syncthreads();
    // ---- prologue: stage hc=0 into buffer 0 ----
    #pragma unroll
    for (int i = 0; i < 4; ++i) {
      int row = (i*4 + wave)*8 + xrow_lo;
      int slotr = base_e + mch*128 + row;
      if (slotr > NSLOT-1) slotr = NSLOT-1;
      const unsigned short* src = hbuf + (size_t)slotr*DFFN + ((xpc ^ (row & 7)) * 8);
      gl16(src, &hs[0][(i*4 + wave)*8*64]);
    }
    #pragma unroll
    for (int i = 0; i < 4; ++i) {
      int idx = i*256 + tid, row = idx >> 4, c4 = idx & 15;
      wdr[i] = *(const float4*)(wd_base + (size_t)row*DFFN + c4*4);
    }
    #pragma unroll
    for (int i = 0; i < 4; ++i) {
      int idx = i*256 + tid, row = idx >> 4, c4 = idx & 15;
      st_bf16x4(dwS[0], row, c4, wdr[i]);
    }
    __syncthreads();

    f32x4 acc[4][2];
    #pragma unroll
    for (int t = 0; t < 4; ++t)
      #pragma unroll
      for (int j = 0; j < 2; ++j) { f32x4 z = {0.f,0.f,0.f,0.f}; acc[t][j] = z; }

    for (int hc = 0; hc < DFFN/64; ++hc) {
      const int cur = hc & 1, nxt = cur ^ 1;
      const bool pf = (hc + 1 < DFFN/64);
      if (pf) {
        #pragma unroll
        for (int i = 0; i < 4; ++i) {
          int row = (i*4 + wave)*8 + xrow_lo;
          int slotr = base_e + mch*128 + row;
          if (slotr > NSLOT-1) slotr = NSLOT-1;
          const unsigned short* src = hbuf + (size_t)slotr*DFFN + (hc+1)*64
                                          + ((xpc ^ (row & 7)) * 8);
          gl16(src, &hs[nxt][(i*4 + wave)*8*64]);
        }
        #pragma unroll
        for (int i = 0; i < 4; ++i) {
          int idx = i*256 + tid, row = idx >> 4, c4 = idx & 15;
          wdr[i] = *(const float4*)(wd_base + (size_t)row*DFFN + (hc+1)*64 + c4*4);
        }
      }
      #pragma unroll
      for (int kk = 0; kk < 2; ++kk) {
        int chunk = kk*4 + (lane >> 4);
        bf16x8 a[4], b[2];
        #pragma unroll
        for (int t = 0; t < 4; ++t) a[t] = ld_frag(hs[cur], wm*64 + t*16 + (lane & 15), chunk);
        #pragma unroll
        for (int j = 0; j < 2; ++j) b[j] = ld_frag(dwS[cur], wh*32 + j*16 + (lane & 15), chunk);
        #pragma unroll
        for (int t = 0; t < 4; ++t)
          #pragma unroll
          for (int j = 0; j < 2; ++j)
            acc[t][j] = __builtin_amdgcn_mfma_f32_16x16x32_bf16(a[t], b[j], acc[t][j], 0, 0, 0);
      }
      if (pf) {
        #pragma unroll
        for (int i = 0; i < 4; ++i) {
          int idx = i*256 + tid, row = idx >> 4, c4 = idx & 15;
          st_bf16x4(dwS[nxt], row, c4, wdr[i]);
        }
      }
      __syncthreads();
    }

    // ---- epilogue -> per-slot partial rows ----
    #pragma unroll
    for (int t = 0; t < 4; ++t)
      #pragma unroll
      for (int j = 0; j < 2; ++j)
        #pragma unroll
        for (int r = 0; r < 4; ++r) {
          int ml = wm*64 + t*16 + (lane >> 4)*4 + r;
          if (mch*128 + ml < n_e) {
            int slot = base_e + mch*128 + ml;
            ypart[(size_t)slot*DMODEL + ct*64 + wh*32 + j*16 + (lane & 15)] =
                f2b_rne(acc[t][j][r]);
          }
        }
  }
}

// ---------------- K6: combine 4 expert partials per token -> fp32 out ----------------
__global__ void k_combine(const unsigned short* __restrict__ ypart,
                          const int* __restrict__ slotnk, float* __restrict__ out) {
  int n = blockIdx.x, tid = threadIdx.x;
  int c0 = tid * 8;
  float acc[8] = {0.f,0.f,0.f,0.f,0.f,0.f,0.f,0.f};
  #pragma unroll
  for (int k = 0; k < TOPK; ++k) {
    int slot = slotnk[n*TOPK + k];
    uint4 v = *(const uint4*)(ypart + (size_t)slot*DMODEL + c0);
    const unsigned short* p = (const unsigned short*)&v;
    #pragma unroll
    for (int j = 0; j < 8; ++j) acc[j] += b2f(p[j]);
  }
  float4 o0 = {acc[0], acc[1], acc[2], acc[3]};
  float4 o1 = {acc[4], acc[5], acc[6], acc[7]};
  *(float4*)(out + (size_t)n*DMODEL + c0)     = o0;
  *(float4*)(out + (size_t)n*DMODEL + c0 + 4) = o1;
}

// ---------------- launcher ----------------
extern "C" void kernel_launch(void* const* d_in, const int* in_sizes, int n_in,
                              void* d_out, int out_size, void* d_ws, size_t ws_size,
                              hipStream_t stream) {
  const float* x     = (const float*)d_in[0];
  const float* W_up  = (const float*)d_in[1];
  const float* W_gt  = (const float*)d_in[2];
  const float* W_dn  = (const float*)d_in[3];
  const float* g_in  = (const float*)d_in[4];
  float* out = (float*)d_out;
  char* ws = (char*)d_ws;

  int*   counts = (int*)(ws + O_COUNTS);
  int*   basep  = (int*)(ws + O_BASE);
  int*   cursor = (int*)(ws + O_CURSOR);
  int*   topi   = (int*)(ws + O_TOPI);
  float* topw   = (float*)(ws + O_TOPW);
  int*   tok    = (int*)(ws + O_TOK);
  float* wgt    = (float*)(ws + O_WGT);
  int*   slotnk = (int*)(ws + O_SLOTNK);
  unsigned short* xg    = (unsigned short*)(ws + O_XG);
  unsigned short* hbuf  = (unsigned short*)(ws + O_HBUF);
  unsigned short* ypart = xg;   // alias: xg dead after k_upgate

  k_zero   <<<1, 64, 0, stream>>>(counts, cursor);
  k_gate   <<<NTOK, 256, 0, stream>>>(x, g_in, topi, topw, counts);
  k_prefix <<<1, 64, 0, stream>>>(counts, basep);
  k_scatter<<<4, 256, 0, stream>>>(topi, topw, basep, cursor, tok, wgt, slotnk);
  k_gather <<<NSLOT, 256, 0, stream>>>(x, tok, xg);
  k_upgate <<<EXP*HT_TILES, 256, 0, stream>>>(xg, W_up, W_gt, counts, basep, wgt, hbuf);
  k_down   <<<EXP*CT_TILES, 256, 0, stream>>>(hbuf, W_dn, counts, basep, ypart);
  k_combine<<<NTOK, 256, 0, stream>>>(ypart, slotnk, out);
}

// Round 3
// 970.302 us; speedup vs baseline: 1.1689x; 1.1689x over previous
//
#include <hip/hip_runtime.h>
#include <math.h>

// ---------------- problem constants ----------------
#define NTOK   1024      // B*T
#define EXP    16
#define TOPK   4
#define DMODEL 2048
#define DFFN   3584
#define HT_TILES 56      // DFFN/64
#define CT_TILES 32      // DMODEL/64
#define NSLOT  4096      // NTOK*TOPK, always exactly filled

typedef __attribute__((ext_vector_type(8))) short bf16x8;
typedef __attribute__((ext_vector_type(4))) float f32x4;

// ---------------- workspace layout (bytes) ----------------
#define O_COUNTS 0
#define O_BASE   256
#define O_CURSOR 512
#define O_TOPI   4096
#define O_TOPW   (O_TOPI + 16384)
#define O_TOK    (O_TOPW + 16384)
#define O_WGT    (O_TOK + 16384)
#define O_SLOTNK (O_WGT + 16384)
#define O_XG     (O_SLOTNK + 16384)                 // bf16 [4096][2048] = 16.78 MB
#define O_HBUF   (O_XG + (size_t)NSLOT*DMODEL*2)    // bf16 [4096][3584] = 29.36 MB
// ypart aliases xg: xg dead after k_upgate, ypart born in k_down.

__device__ __forceinline__ unsigned short f2b_rne(float f) {
  unsigned u = __builtin_bit_cast(unsigned, f);
  u += 0x7FFFu + ((u >> 16) & 1u);
  return (unsigned short)(u >> 16);
}
__device__ __forceinline__ float b2f(unsigned short h) {
  unsigned u = ((unsigned)h) << 16;
  return __builtin_bit_cast(float, u);
}
// packed fp32x2 -> bf16x2 (RNE), single VALU op
__device__ __forceinline__ unsigned pk2(float lo, float hi) {
  unsigned r;
  asm("v_cvt_pk_bf16_f32 %0, %1, %2" : "=v"(r) : "v"(lo), "v"(hi));
  return r;
}
// 8 consecutive fp32 (two float4) -> bf16x8 MFMA fragment
__device__ __forceinline__ bf16x8 pack8(float4 a, float4 b) {
  union { unsigned u[4]; bf16x8 v; } r;
  r.u[0] = pk2(a.x, a.y); r.u[1] = pk2(a.z, a.w);
  r.u[2] = pk2(b.x, b.y); r.u[3] = pk2(b.z, b.w);
  return r.v;
}

// async 16B global->LDS (wave-uniform LDS base + lane*16; per-lane global src)
__device__ __forceinline__ void gl16(const unsigned short* g, unsigned short* l) {
  __builtin_amdgcn_global_load_lds(
      (const __attribute__((address_space(1))) void*)g,
      (__attribute__((address_space(3))) void*)l, 16, 0, 0);
}

// read one MFMA fragment (8 bf16 = 16B) from swizzled LDS tile (row stride 64)
__device__ __forceinline__ bf16x8 ld_frag(const unsigned short* lds, int row, int chunk) {
  return *(const bf16x8*)(lds + row*64 + ((chunk ^ (row & 7)) * 8));
}

// ---------------- K0: zero counters ----------------
__global__ void k_zero(int* counts, int* cursor) {
  int t = threadIdx.x;
  if (t < EXP) { counts[t] = 0; cursor[t] = 0; }
}

// ---------------- K1: router (fp32, exact top-4 like lax.top_k) ----------------
__global__ void k_gate(const float* __restrict__ x, const float* __restrict__ gi,
                       int* __restrict__ topi, float* __restrict__ topw,
                       int* __restrict__ counts) {
  int n = blockIdx.x;
  int lane = threadIdx.x & 63, wave = threadIdx.x >> 6;
  __shared__ float lg[EXP];
  const float4* xr = (const float4*)(x + (size_t)n * DMODEL);
  #pragma unroll
  for (int i = 0; i < 4; ++i) {
    int e = wave * 4 + i;
    const float4* gr = (const float4*)(gi + (size_t)e * DMODEL);
    float s = 0.f;
    #pragma unroll
    for (int j = 0; j < 8; ++j) {
      float4 a = xr[j*64 + lane];
      float4 b = gr[j*64 + lane];
      s += a.x*b.x + a.y*b.y + a.z*b.z + a.w*b.w;
    }
    #pragma unroll
    for (int off = 32; off; off >>= 1) s += __shfl_xor(s, off);
    if (lane == 0) lg[e] = s;
  }
  __syncthreads();
  if (threadIdx.x == 0) {
    float v[EXP];
    #pragma unroll
    for (int j = 0; j < EXP; ++j) v[j] = lg[j];
    int bi[TOPK]; float bv[TOPK];
    #pragma unroll
    for (int k = 0; k < TOPK; ++k) {
      float best = -3.4e38f; int bidx = 0;
      for (int j = 0; j < EXP; ++j) if (v[j] > best) { best = v[j]; bidx = j; }
      bv[k] = best; bi[k] = bidx; v[bidx] = -3.4e38f;
    }
    float m = bv[0], ss = 0.f, w[TOPK];
    #pragma unroll
    for (int k = 0; k < TOPK; ++k) { w[k] = expf(bv[k] - m); ss += w[k]; }
    #pragma unroll
    for (int k = 0; k < TOPK; ++k) {
      topi[n*TOPK + k] = bi[k];
      topw[n*TOPK + k] = w[k] / ss;
      atomicAdd(&counts[bi[k]], 1);
    }
  }
}

// ---------------- K2: exclusive prefix over 16 counts ----------------
__global__ void k_prefix(const int* __restrict__ counts, int* __restrict__ basep) {
  if (threadIdx.x == 0) {
    int acc = 0;
    for (int e = 0; e < EXP; ++e) { basep[e] = acc; acc += counts[e]; }
  }
}

// ---------------- K3: scatter assignments into expert-sorted slots ----------------
__global__ void k_scatter(const int* __restrict__ topi, const float* __restrict__ topw,
                          const int* __restrict__ basep, int* __restrict__ cursor,
                          int* __restrict__ tok, float* __restrict__ wgt,
                          int* __restrict__ slotnk) {
  int n = blockIdx.x * blockDim.x + threadIdx.x;
  if (n >= NTOK) return;
  #pragma unroll
  for (int k = 0; k < TOPK; ++k) {
    int e = topi[n*TOPK + k];
    int pos = atomicAdd(&cursor[e], 1);
    int slot = basep[e] + pos;
    tok[slot] = n;
    wgt[slot] = topw[n*TOPK + k];
    slotnk[n*TOPK + k] = slot;
  }
}

// ---------------- K3b: gather x rows into expert-sorted bf16 buffer ----------------
__global__ void k_gather(const float* __restrict__ x, const int* __restrict__ tok,
                         unsigned short* __restrict__ xg) {
  int slot = blockIdx.x;
  int t = tok[slot];
  int c0 = threadIdx.x * 8;
  const float* src = x + (size_t)t * DMODEL + c0;
  float4 a = *(const float4*)(src);
  float4 b = *(const float4*)(src + 4);
  uint4 o = {pk2(a.x, a.y), pk2(a.z, a.w), pk2(b.x, b.y), pk2(b.z, b.w)};
  *(uint4*)(xg + (size_t)slot * DMODEL + c0) = o;
}

// ---------------- K4: fused up+gate, weights streamed direct to registers -------
// grid: e*HT_TILES + ht ; block 256 = 4 waves. Wave w owns H rows
// [ht*64 + w*16, +16) x all 128 M rows of the chunk. Weight B-fragments are
// loaded straight from HBM (8 consecutive fp32 per lane = 2x dwordx4),
// converted via v_cvt_pk_bf16_f32. LDS holds only the x A-tile (2x16KB dbuf).
__global__ __launch_bounds__(256, 3) void k_upgate(
    const unsigned short* __restrict__ xg,
    const float* __restrict__ Wu, const float* __restrict__ Wg,
    const int* __restrict__ counts, const int* __restrict__ basep,
    const float* __restrict__ wgt,
    unsigned short* __restrict__ hbuf) {
  int e  = blockIdx.x / HT_TILES;
  int ht = blockIdx.x % HT_TILES;
  int n_e = counts[e];
  if (n_e == 0) return;
  int base_e = basep[e];
  int nm = (n_e + 127) >> 7;

  __shared__ unsigned short xs[2][128*64];
  __shared__ float swgt[128];

  int tid = threadIdx.x;
  int lane = tid & 63, wave = tid >> 6;
  int col = lane & 15;                 // n-index (h) within the wave's 16 rows
  int kgrp = (lane >> 4) * 8;          // k sub-offset within a 32-wide k group
  const float* wu_row = Wu + ((size_t)e * DFFN + (size_t)(ht*64 + wave*16 + col)) * DMODEL + kgrp;
  const float* wg_row = Wg + ((size_t)e * DFFN + (size_t)(ht*64 + wave*16 + col)) * DMODEL + kgrp;

  int xrow_lo = lane >> 3;             // 0..7
  int xpc     = lane & 7;              // physical 16B chunk in row

  for (int mch = 0; mch < nm; ++mch) {
    __syncthreads();                   // protect xs + swgt reuse across chunks
    if (tid < 128) {
      int r = mch*128 + tid;
      swgt[tid] = (r < n_e) ? wgt[base_e + r] : 0.f;
    }
    // prologue: stage kc=0 into buffer 0
    #pragma unroll
    for (int i = 0; i < 4; ++i) {
      int row = (i*4 + wave)*8 + xrow_lo;
      int slotr = base_e + mch*128 + row;
      if (slotr > NSLOT-1) slotr = NSLOT-1;
      gl16(xg + (size_t)slotr*DMODEL + ((xpc ^ (row & 7)) * 8),
           &xs[0][(i*4 + wave)*8*64]);
    }

    f32x4 ua[8], ga[8];
    #pragma unroll
    for (int t = 0; t < 8; ++t) { f32x4 z = {0.f,0.f,0.f,0.f}; ua[t] = z; ga[t] = z; }

    for (int kc = 0; kc < DMODEL/64; ++kc) {
      const int cur = kc & 1;
      __syncthreads();                 // buf[cur] staged (drains gl16)
      if (kc + 1 < DMODEL/64) {
        #pragma unroll
        for (int i = 0; i < 4; ++i) {
          int row = (i*4 + wave)*8 + xrow_lo;
          int slotr = base_e + mch*128 + row;
          if (slotr > NSLOT-1) slotr = NSLOT-1;
          gl16(xg + (size_t)slotr*DMODEL + (kc+1)*64 + ((xpc ^ (row & 7)) * 8),
               &xs[cur ^ 1][(i*4 + wave)*8*64]);
        }
      }
      // weight loads for this k-slab: 8x dwordx4, direct to regs
      const float* pu = wu_row + kc*64;
      const float* pg = wg_row + kc*64;
      float4 u0a = *(const float4*)(pu);
      float4 u0b = *(const float4*)(pu + 4);
      float4 u1a = *(const float4*)(pu + 32);
      float4 u1b = *(const float4*)(pu + 36);
      float4 g0a = *(const float4*)(pg);
      float4 g0b = *(const float4*)(pg + 4);
      float4 g1a = *(const float4*)(pg + 32);
      float4 g1b = *(const float4*)(pg + 36);
      bf16x8 bu0 = pack8(u0a, u0b), bu1 = pack8(u1a, u1b);
      bf16x8 bg0 = pack8(g0a, g0b), bg1 = pack8(g1a, g1b);
      #pragma unroll
      for (int kk = 0; kk < 2; ++kk) {
        int chunk = kk*4 + (lane >> 4);
        bf16x8 bu = kk ? bu1 : bu0;
        bf16x8 bg = kk ? bg1 : bg0;
        #pragma unroll
        for (int t = 0; t < 8; ++t) {
          bf16x8 a = ld_frag(xs[cur], t*16 + col, chunk);
          ua[t] = __builtin_amdgcn_mfma_f32_16x16x32_bf16(a, bu, ua[t], 0, 0, 0);
          ga[t] = __builtin_amdgcn_mfma_f32_16x16x32_bf16(a, bg, ga[t], 0, 0, 0);
        }
      }
    }

    // epilogue: h = silu(g)*u * gate_weight -> bf16 hbuf
    #pragma unroll
    for (int t = 0; t < 8; ++t)
      #pragma unroll
      for (int r = 0; r < 4; ++r) {
        int ml = t*16 + (lane >> 4)*4 + r;
        if (mch*128 + ml < n_e) {
          float u = ua[t][r], g = ga[t][r];
          float hv = u * (g / (1.f + expf(-g))) * swgt[ml];
          int slot = base_e + mch*128 + ml;
          hbuf[(size_t)slot*DFFN + ht*64 + wave*16 + col] = f2b_rne(hv);
        }
      }
  }
}

// ---------------- K5: down-proj, weights streamed direct to registers ----------
__global__ __launch_bounds__(256, 4) void k_down(
    const unsigned short* __restrict__ hbuf, const float* __restrict__ Wd,
    const int* __restrict__ counts, const int* __restrict__ basep,
    unsigned short* __restrict__ ypart) {
  int e  = blockIdx.x / CT_TILES;
  int ct = blockIdx.x % CT_TILES;
  int n_e = counts[e];
  if (n_e == 0) return;
  int base_e = basep[e];
  int nm = (n_e + 127) >> 7;

  __shared__ unsigned short hs[2][128*64];

  int tid = threadIdx.x;
  int lane = tid & 63, wave = tid >> 6;
  int col = lane & 15;
  int kgrp = (lane >> 4) * 8;
  const float* wd_row = Wd + ((size_t)e * DMODEL + (size_t)(ct*64 + wave*16 + col)) * DFFN + kgrp;

  int xrow_lo = lane >> 3;
  int xpc     = lane & 7;

  for (int mch = 0; mch < nm; ++mch) {
    __syncthreads();
    #pragma unroll
    for (int i = 0; i < 4; ++i) {
      int row = (i*4 + wave)*8 + xrow_lo;
      int slotr = base_e + mch*128 + row;
      if (slotr > NSLOT-1) slotr = NSLOT-1;
      gl16(hbuf + (size_t)slotr*DFFN + ((xpc ^ (row & 7)) * 8),
           &hs[0][(i*4 + wave)*8*64]);
    }

    f32x4 acc[8];
    #pragma unroll
    for (int t = 0; t < 8; ++t) { f32x4 z = {0.f,0.f,0.f,0.f}; acc[t] = z; }

    for (int hc = 0; hc < DFFN/64; ++hc) {
      const int cur = hc & 1;
      __syncthreads();
      if (hc + 1 < DFFN/64) {
        #pragma unroll
        for (int i = 0; i < 4; ++i) {
          int row = (i*4 + wave)*8 + xrow_lo;
          int slotr = base_e + mch*128 + row;
          if (slotr > NSLOT-1) slotr = NSLOT-1;
          gl16(hbuf + (size_t)slotr*DFFN + (hc+1)*64 + ((xpc ^ (row & 7)) * 8),
               &hs[cur ^ 1][(i*4 + wave)*8*64]);
        }
      }
      const float* pd = wd_row + hc*64;
      float4 d0a = *(const float4*)(pd);
      float4 d0b = *(const float4*)(pd + 4);
      float4 d1a = *(const float4*)(pd + 32);
      float4 d1b = *(const float4*)(pd + 36);
      bf16x8 bd0 = pack8(d0a, d0b), bd1 = pack8(d1a, d1b);
      #pragma unroll
      for (int kk = 0; kk < 2; ++kk) {
        int chunk = kk*4 + (lane >> 4);
        bf16x8 bd = kk ? bd1 : bd0;
        #pragma unroll
        for (int t = 0; t < 8; ++t) {
          bf16x8 a = ld_frag(hs[cur], t*16 + col, chunk);
          acc[t] = __builtin_amdgcn_mfma_f32_16x16x32_bf16(a, bd, acc[t], 0, 0, 0);
        }
      }
    }

    #pragma unroll
    for (int t = 0; t < 8; ++t)
      #pragma unroll
      for (int r = 0; r < 4; ++r) {
        int ml = t*16 + (lane >> 4)*4 + r;
        if (mch*128 + ml < n_e) {
          int slot = base_e + mch*128 + ml;
          ypart[(size_t)slot*DMODEL + ct*64 + wave*16 + col] = f2b_rne(acc[t][r]);
        }
      }
  }
}

// ---------------- K6: combine 4 expert partials per token -> fp32 out ----------------
__global__ void k_combine(const unsigned short* __restrict__ ypart,
                          const int* __restrict__ slotnk, float* __restrict__ out) {
  int n = blockIdx.x, tid = threadIdx.x;
  int c0 = tid * 8;
  float acc[8] = {0.f,0.f,0.f,0.f,0.f,0.f,0.f,0.f};
  #pragma unroll
  for (int k = 0; k < TOPK; ++k) {
    int slot = slotnk[n*TOPK + k];
    uint4 v = *(const uint4*)(ypart + (size_t)slot*DMODEL + c0);
    const unsigned short* p = (const unsigned short*)&v;
    #pragma unroll
    for (int j = 0; j < 8; ++j) acc[j] += b2f(p[j]);
  }
  float4 o0 = {acc[0], acc[1], acc[2], acc[3]};
  float4 o1 = {acc[4], acc[5], acc[6], acc[7]};
  *(float4*)(out + (size_t)n*DMODEL + c0)     = o0;
  *(float4*)(out + (size_t)n*DMODEL + c0 + 4) = o1;
}

// ---------------- launcher ----------------
extern "C" void kernel_launch(void* const* d_in, const int* in_sizes, int n_in,
                              void* d_out, int out_size, void* d_ws, size_t ws_size,
                              hipStream_t stream) {
  const float* x     = (const float*)d_in[0];
  const float* W_up  = (const float*)d_in[1];
  const float* W_gt  = (const float*)d_in[2];
  const float* W_dn  = (const float*)d_in[3];
  const float* g_in  = (const float*)d_in[4];
  float* out = (float*)d_out;
  char* ws = (char*)d_ws;

  int*   counts = (int*)(ws + O_COUNTS);
  int*   basep  = (int*)(ws + O_BASE);
  int*   cursor = (int*)(ws + O_CURSOR);
  int*   topi   = (int*)(ws + O_TOPI);
  float* topw   = (float*)(ws + O_TOPW);
  int*   tok    = (int*)(ws + O_TOK);
  float* wgt    = (float*)(ws + O_WGT);
  int*   slotnk = (int*)(ws + O_SLOTNK);
  unsigned short* xg    = (unsigned short*)(ws + O_XG);
  unsigned short* hbuf  = (unsigned short*)(ws + O_HBUF);
  unsigned short* ypart = xg;   // alias: xg dead after k_upgate

  k_zero   <<<1, 64, 0, stream>>>(counts, cursor);
  k_gate   <<<NTOK, 256, 0, stream>>>(x, g_in, topi, topw, counts);
  k_prefix <<<1, 64, 0, stream>>>(counts, basep);
  k_scatter<<<4, 256, 0, stream>>>(topi, topw, basep, cursor, tok, wgt, slotnk);
  k_gather <<<NSLOT, 256, 0, stream>>>(x, tok, xg);
  k_upgate <<<EXP*HT_TILES, 256, 0, stream>>>(xg, W_up, W_gt, counts, basep, wgt, hbuf);
  k_down   <<<EXP*CT_TILES, 256, 0, stream>>>(hbuf, W_dn, counts, basep, ypart);
  k_combine<<<NTOK, 256, 0, stream>>>(ypart, slotnk, out);
}

// Round 4
// 772.345 us; speedup vs baseline: 1.4685x; 1.2563x over previous
//
#include <hip/hip_runtime.h>
#include <math.h>

// ---------------- problem constants ----------------
#define NTOK   1024      // B*T
#define EXP    16
#define TOPK   4
#define DMODEL 2048
#define DFFN   3584
#define HT_TILES 56      // DFFN/64
#define CT_TILES 32      // DMODEL/64
#define NSLOT  4096      // NTOK*TOPK, always exactly filled
#define NCHMAX 48        // max sum of ceil(n_e/128) = 47, padded

typedef __attribute__((ext_vector_type(8))) short bf16x8;
typedef __attribute__((ext_vector_type(4))) float f32x4;

// ---------------- workspace layout (bytes) ----------------
#define O_COUNTS 0
#define O_BASE   256
#define O_CURSOR 512
#define O_CHT    1024                               // int[1+NCHMAX] chunk table
#define O_TOPI   4096
#define O_TOPW   (O_TOPI + 16384)
#define O_TOK    (O_TOPW + 16384)
#define O_WGT    (O_TOK + 16384)
#define O_SLOTNK (O_WGT + 16384)
#define O_XG     (O_SLOTNK + 16384)                 // bf16 [4096][2048] = 16.78 MB
#define O_HBUF   (O_XG + (size_t)NSLOT*DMODEL*2)    // bf16 [4096][3584] = 29.36 MB
// ypart aliases xg: xg dead after k_upgate, ypart born in k_down.

#define VMW(N) asm volatile("s_waitcnt vmcnt(" #N ")" ::: "memory")
#define LKW0() asm volatile("s_waitcnt lgkmcnt(0)" ::: "memory")
#define BAR()  __builtin_amdgcn_s_barrier()

__device__ __forceinline__ unsigned short f2b_rne(float f) {
  unsigned u = __builtin_bit_cast(unsigned, f);
  u += 0x7FFFu + ((u >> 16) & 1u);
  return (unsigned short)(u >> 16);
}
__device__ __forceinline__ float b2f(unsigned short h) {
  unsigned u = ((unsigned)h) << 16;
  return __builtin_bit_cast(float, u);
}
__device__ __forceinline__ unsigned pk2(float lo, float hi) {
  unsigned r;
  asm("v_cvt_pk_bf16_f32 %0, %1, %2" : "=v"(r) : "v"(lo), "v"(hi));
  return r;
}
__device__ __forceinline__ bf16x8 pack8(float4 a, float4 b) {
  union { unsigned u[4]; bf16x8 v; } r;
  r.u[0] = pk2(a.x, a.y); r.u[1] = pk2(a.z, a.w);
  r.u[2] = pk2(b.x, b.y); r.u[3] = pk2(b.z, b.w);
  return r.v;
}

// async 16B global->LDS (wave-uniform LDS base + lane*16; per-lane global src)
__device__ __forceinline__ void gl16(const unsigned short* g, unsigned short* l) {
  __builtin_amdgcn_global_load_lds(
      (const __attribute__((address_space(1))) void*)g,
      (__attribute__((address_space(3))) void*)l, 16, 0, 0);
}

// read one MFMA fragment (8 bf16 = 16B) from swizzled LDS tile (row stride 64)
__device__ __forceinline__ bf16x8 ld_frag(const unsigned short* lds, int row, int chunk) {
  return *(const bf16x8*)(lds + row*64 + ((chunk ^ (row & 7)) * 8));
}

// ---------------- K0: zero counters ----------------
__global__ void k_zero(int* counts, int* cursor) {
  int t = threadIdx.x;
  if (t < EXP) { counts[t] = 0; cursor[t] = 0; }
}

// ---------------- K1: router (fp32, exact top-4 like lax.top_k) ----------------
__global__ void k_gate(const float* __restrict__ x, const float* __restrict__ gi,
                       int* __restrict__ topi, float* __restrict__ topw,
                       int* __restrict__ counts) {
  int n = blockIdx.x;
  int lane = threadIdx.x & 63, wave = threadIdx.x >> 6;
  __shared__ float lg[EXP];
  const float4* xr = (const float4*)(x + (size_t)n * DMODEL);
  #pragma unroll
  for (int i = 0; i < 4; ++i) {
    int e = wave * 4 + i;
    const float4* gr = (const float4*)(gi + (size_t)e * DMODEL);
    float s = 0.f;
    #pragma unroll
    for (int j = 0; j < 8; ++j) {
      float4 a = xr[j*64 + lane];
      float4 b = gr[j*64 + lane];
      s += a.x*b.x + a.y*b.y + a.z*b.z + a.w*b.w;
    }
    #pragma unroll
    for (int off = 32; off; off >>= 1) s += __shfl_xor(s, off);
    if (lane == 0) lg[e] = s;
  }
  __syncthreads();
  if (threadIdx.x == 0) {
    float v[EXP];
    #pragma unroll
    for (int j = 0; j < EXP; ++j) v[j] = lg[j];
    int bi[TOPK]; float bv[TOPK];
    #pragma unroll
    for (int k = 0; k < TOPK; ++k) {
      float best = -3.4e38f; int bidx = 0;
      for (int j = 0; j < EXP; ++j) if (v[j] > best) { best = v[j]; bidx = j; }
      bv[k] = best; bi[k] = bidx; v[bidx] = -3.4e38f;
    }
    float m = bv[0], ss = 0.f, w[TOPK];
    #pragma unroll
    for (int k = 0; k < TOPK; ++k) { w[k] = expf(bv[k] - m); ss += w[k]; }
    #pragma unroll
    for (int k = 0; k < TOPK; ++k) {
      topi[n*TOPK + k] = bi[k];
      topw[n*TOPK + k] = w[k] / ss;
      atomicAdd(&counts[bi[k]], 1);
    }
  }
}

// ---------------- K2: prefix + chunk table ----------------
__global__ void k_prefix(const int* __restrict__ counts, int* __restrict__ basep,
                         int* __restrict__ chtab) {
  if (threadIdx.x == 0) {
    int acc = 0;
    for (int e = 0; e < EXP; ++e) { basep[e] = acc; acc += counts[e]; }
    int c = 0;
    for (int e = 0; e < EXP; ++e) {
      int nm = (counts[e] + 127) >> 7;
      for (int m = 0; m < nm; ++m) { chtab[1 + c] = (e << 8) | m; ++c; }
    }
    chtab[0] = c;
    for (; c < NCHMAX; ++c) chtab[1 + c] = -1;
  }
}

// ---------------- K3: scatter assignments into expert-sorted slots ----------------
__global__ void k_scatter(const int* __restrict__ topi, const float* __restrict__ topw,
                          const int* __restrict__ basep, int* __restrict__ cursor,
                          int* __restrict__ tok, float* __restrict__ wgt,
                          int* __restrict__ slotnk) {
  int n = blockIdx.x * blockDim.x + threadIdx.x;
  if (n >= NTOK) return;
  #pragma unroll
  for (int k = 0; k < TOPK; ++k) {
    int e = topi[n*TOPK + k];
    int pos = atomicAdd(&cursor[e], 1);
    int slot = basep[e] + pos;
    tok[slot] = n;
    wgt[slot] = topw[n*TOPK + k];
    slotnk[n*TOPK + k] = slot;
  }
}

// ---------------- K3b: gather x rows into expert-sorted bf16 buffer ----------------
__global__ void k_gather(const float* __restrict__ x, const int* __restrict__ tok,
                         unsigned short* __restrict__ xg) {
  int slot = blockIdx.x;
  int t = tok[slot];
  int c0 = threadIdx.x * 8;
  const float* src = x + (size_t)t * DMODEL + c0;
  float4 a = *(const float4*)(src);
  float4 b = *(const float4*)(src + 4);
  uint4 o = {pk2(a.x, a.y), pk2(a.z, a.w), pk2(b.x, b.y), pk2(b.z, b.w)};
  *(uint4*)(xg + (size_t)slot * DMODEL + c0) = o;
}

// ---------------- K4: fused up+gate, pipelined weight streaming ----------------
// One (chunk, ht) per block; 4 waves; wave w owns H rows [ht*64+w*16, +16) x 128 M.
// Per kc: issue w(kc+1)+gl16(kc+1) -> vmcnt(12) -> barrier -> MFMA(kc) -> vmcnt(4)
// -> pack(kc+1). Raw s_barrier + counted vmcnt keep loads in flight across barriers.
#define UG_STEP(XSC, XSN, PC, PN, KC) do {                                     \
    BAR();                                                                     \
    int kn_ = (KC) + 1; if (kn_ > DMODEL/64 - 1) kn_ = DMODEL/64 - 1;          \
    const float* pu_ = wu_row + kn_*64;                                        \
    const float* pg_ = wg_row + kn_*64;                                        \
    float4 r0_ = *(const float4*)(pu_);                                        \
    float4 r1_ = *(const float4*)(pu_ + 4);                                    \
    float4 r2_ = *(const float4*)(pu_ + 32);                                   \
    float4 r3_ = *(const float4*)(pu_ + 36);                                   \
    float4 r4_ = *(const float4*)(pg_);                                        \
    float4 r5_ = *(const float4*)(pg_ + 4);                                    \
    float4 r6_ = *(const float4*)(pg_ + 32);                                   \
    float4 r7_ = *(const float4*)(pg_ + 36);                                   \
    _Pragma("unroll")                                                          \
    for (int i_ = 0; i_ < 4; ++i_)                                             \
      gl16(bx[i_] + kn_*64, (XSN) + (i_*4 + wave)*8*64);                       \
    VMW(12);                                                                   \
    BAR();                                                                     \
    _Pragma("unroll")                                                          \
    for (int kk_ = 0; kk_ < 2; ++kk_) {                                        \
      int chunk_ = kk_*4 + (lane >> 4);                                        \
      _Pragma("unroll")                                                        \
      for (int t_ = 0; t_ < 8; ++t_) {                                         \
        bf16x8 a_ = ld_frag((XSC), t_*16 + col, chunk_);                       \
        ua[t_] = __builtin_amdgcn_mfma_f32_16x16x32_bf16(a_, PC[kk_],   ua[t_], 0, 0, 0); \
        ga[t_] = __builtin_amdgcn_mfma_f32_16x16x32_bf16(a_, PC[2+kk_], ga[t_], 0, 0, 0); \
      }                                                                        \
    }                                                                          \
    VMW(4);                                                                    \
    PN[0] = pack8(r0_, r1_); PN[1] = pack8(r2_, r3_);                          \
    PN[2] = pack8(r4_, r5_); PN[3] = pack8(r6_, r7_);                          \
  } while (0)

__global__ __launch_bounds__(256, 3) void k_upgate(
    const unsigned short* __restrict__ xg,
    const float* __restrict__ Wu, const float* __restrict__ Wg,
    const int* __restrict__ counts, const int* __restrict__ basep,
    const int* __restrict__ chtab, const float* __restrict__ wgt,
    unsigned short* __restrict__ hbuf) {
  int bid = blockIdx.x;
  int lb  = (bid & 7) * (NCHMAX*HT_TILES/8) + (bid >> 3);   // XCD-bijective swizzle
  int cid = lb % NCHMAX, ht = lb / NCHMAX;
  int ent = chtab[1 + cid];
  if (ent < 0) return;
  int e = ent >> 8, mch = ent & 255;
  int n_e = counts[e], base_e = basep[e], mstart = mch * 128;

  __shared__ unsigned short xs[2][128*64];
  __shared__ float swgt[128];

  int tid = threadIdx.x;
  int lane = tid & 63, wave = tid >> 6;
  int col = lane & 15;                 // B row (h) within wave's 16
  int kgrp = (lane >> 4) * 8;
  const float* wu_row = Wu + ((size_t)e * DFFN + (size_t)(ht*64 + wave*16 + col)) * DMODEL + kgrp;
  const float* wg_row = Wg + ((size_t)e * DFFN + (size_t)(ht*64 + wave*16 + col)) * DMODEL + kgrp;

  int xrow_lo = lane >> 3;             // 0..7
  int xpc     = lane & 7;
  int swz     = (xpc ^ xrow_lo) * 8;   // row&7 == xrow_lo for all i

  // per-lane global x source bases for the 4 gl16 issues
  const unsigned short* bx[4];
  #pragma unroll
  for (int i = 0; i < 4; ++i) {
    int row = (i*4 + wave)*8 + xrow_lo;
    int slotr = base_e + mstart + row;
    if (slotr > NSLOT-1) slotr = NSLOT-1;
    bx[i] = xg + (size_t)slotr*DMODEL + swz;
  }

  if (tid < 128) {
    int r = mstart + tid;
    swgt[tid] = (r < n_e) ? wgt[base_e + r] : 0.f;
  }
  LKW0();

  // prologue: w(0) + x(0)
  bf16x8 pA[4], pB[4];
  {
    const float* pu_ = wu_row;
    const float* pg_ = wg_row;
    float4 r0 = *(const float4*)(pu_);
    float4 r1 = *(const float4*)(pu_ + 4);
    float4 r2 = *(const float4*)(pu_ + 32);
    float4 r3 = *(const float4*)(pu_ + 36);
    float4 r4 = *(const float4*)(pg_);
    float4 r5 = *(const float4*)(pg_ + 4);
    float4 r6 = *(const float4*)(pg_ + 32);
    float4 r7 = *(const float4*)(pg_ + 36);
    #pragma unroll
    for (int i = 0; i < 4; ++i)
      gl16(bx[i], &xs[0][(i*4 + wave)*8*64]);
    VMW(4);
    pA[0] = pack8(r0, r1); pA[1] = pack8(r2, r3);
    pA[2] = pack8(r4, r5); pA[3] = pack8(r6, r7);
  }

  f32x4 ua[8], ga[8];
  #pragma unroll
  for (int t = 0; t < 8; ++t) { f32x4 z = {0.f,0.f,0.f,0.f}; ua[t] = z; ga[t] = z; }

  #pragma unroll 1
  for (int kc = 0; kc < DMODEL/64; kc += 2) {
    UG_STEP(xs[0], xs[1], pA, pB, kc);
    UG_STEP(xs[1], xs[0], pB, pA, kc + 1);
  }

  // epilogue: h = silu(g)*u * gate_weight -> bf16 hbuf
  #pragma unroll
  for (int t = 0; t < 8; ++t)
    #pragma unroll
    for (int r = 0; r < 4; ++r) {
      int ml = t*16 + (lane >> 4)*4 + r;
      if (mstart + ml < n_e) {
        float u = ua[t][r], g = ga[t][r];
        float hv = u * (g / (1.f + expf(-g))) * swgt[ml];
        int slot = base_e + mstart + ml;
        hbuf[(size_t)slot*DFFN + ht*64 + wave*16 + col] = f2b_rne(hv);
      }
    }
}

// ---------------- K5: down-proj, pipelined weight streaming ----------------
#define DN_STEP(XSC, XSN, PC, PN, KC) do {                                     \
    BAR();                                                                     \
    int kn_ = (KC) + 1; if (kn_ > DFFN/64 - 1) kn_ = DFFN/64 - 1;              \
    const float* pd_ = wd_row + kn_*64;                                        \
    float4 r0_ = *(const float4*)(pd_);                                        \
    float4 r1_ = *(const float4*)(pd_ + 4);                                    \
    float4 r2_ = *(const float4*)(pd_ + 32);                                   \
    float4 r3_ = *(const float4*)(pd_ + 36);                                   \
    _Pragma("unroll")                                                          \
    for (int i_ = 0; i_ < 4; ++i_)                                             \
      gl16(bh[i_] + kn_*64, (XSN) + (i_*4 + wave)*8*64);                       \
    VMW(8);                                                                    \
    BAR();                                                                     \
    _Pragma("unroll")                                                          \
    for (int kk_ = 0; kk_ < 2; ++kk_) {                                        \
      int chunk_ = kk_*4 + (lane >> 4);                                        \
      _Pragma("unroll")                                                        \
      for (int t_ = 0; t_ < 8; ++t_) {                                         \
        bf16x8 a_ = ld_frag((XSC), t_*16 + col, chunk_);                       \
        acc[t_] = __builtin_amdgcn_mfma_f32_16x16x32_bf16(a_, PC[kk_], acc[t_], 0, 0, 0); \
      }                                                                        \
    }                                                                          \
    VMW(4);                                                                    \
    PN[0] = pack8(r0_, r1_); PN[1] = pack8(r2_, r3_);                          \
  } while (0)

__global__ __launch_bounds__(256, 4) void k_down(
    const unsigned short* __restrict__ hbuf, const float* __restrict__ Wd,
    const int* __restrict__ counts, const int* __restrict__ basep,
    const int* __restrict__ chtab,
    unsigned short* __restrict__ ypart) {
  int bid = blockIdx.x;
  int lb  = (bid & 7) * (NCHMAX*CT_TILES/8) + (bid >> 3);
  int cid = lb % NCHMAX, ct = lb / NCHMAX;
  int ent = chtab[1 + cid];
  if (ent < 0) return;
  int e = ent >> 8, mch = ent & 255;
  int n_e = counts[e], base_e = basep[e], mstart = mch * 128;

  __shared__ unsigned short hs[2][128*64];

  int tid = threadIdx.x;
  int lane = tid & 63, wave = tid >> 6;
  int col = lane & 15;
  int kgrp = (lane >> 4) * 8;
  const float* wd_row = Wd + ((size_t)e * DMODEL + (size_t)(ct*64 + wave*16 + col)) * DFFN + kgrp;

  int xrow_lo = lane >> 3;
  int xpc     = lane & 7;
  int swz     = (xpc ^ xrow_lo) * 8;

  const unsigned short* bh[4];
  #pragma unroll
  for (int i = 0; i < 4; ++i) {
    int row = (i*4 + wave)*8 + xrow_lo;
    int slotr = base_e + mstart + row;
    if (slotr > NSLOT-1) slotr = NSLOT-1;
    bh[i] = hbuf + (size_t)slotr*DFFN + swz;
  }

  bf16x8 pA[2], pB[2];
  {
    const float* pd_ = wd_row;
    float4 r0 = *(const float4*)(pd_);
    float4 r1 = *(const float4*)(pd_ + 4);
    float4 r2 = *(const float4*)(pd_ + 32);
    float4 r3 = *(const float4*)(pd_ + 36);
    #pragma unroll
    for (int i = 0; i < 4; ++i)
      gl16(bh[i], &hs[0][(i*4 + wave)*8*64]);
    VMW(4);
    pA[0] = pack8(r0, r1); pA[1] = pack8(r2, r3);
  }

  f32x4 acc[8];
  #pragma unroll
  for (int t = 0; t < 8; ++t) { f32x4 z = {0.f,0.f,0.f,0.f}; acc[t] = z; }

  #pragma unroll 1
  for (int hc = 0; hc < DFFN/64; hc += 2) {
    DN_STEP(hs[0], hs[1], pA, pB, hc);
    DN_STEP(hs[1], hs[0], pB, pA, hc + 1);
  }

  #pragma unroll
  for (int t = 0; t < 8; ++t)
    #pragma unroll
    for (int r = 0; r < 4; ++r) {
      int ml = t*16 + (lane >> 4)*4 + r;
      if (mstart + ml < n_e) {
        int slot = base_e + mstart + ml;
        ypart[(size_t)slot*DMODEL + ct*64 + wave*16 + col] = f2b_rne(acc[t][r]);
      }
    }
}

// ---------------- K6: combine 4 expert partials per token -> fp32 out ----------------
__global__ void k_combine(const unsigned short* __restrict__ ypart,
                          const int* __restrict__ slotnk, float* __restrict__ out) {
  int n = blockIdx.x, tid = threadIdx.x;
  int c0 = tid * 8;
  float acc[8] = {0.f,0.f,0.f,0.f,0.f,0.f,0.f,0.f};
  #pragma unroll
  for (int k = 0; k < TOPK; ++k) {
    int slot = slotnk[n*TOPK + k];
    uint4 v = *(const uint4*)(ypart + (size_t)slot*DMODEL + c0);
    const unsigned short* p = (const unsigned short*)&v;
    #pragma unroll
    for (int j = 0; j < 8; ++j) acc[j] += b2f(p[j]);
  }
  float4 o0 = {acc[0], acc[1], acc[2], acc[3]};
  float4 o1 = {acc[4], acc[5], acc[6], acc[7]};
  *(float4*)(out + (size_t)n*DMODEL + c0)     = o0;
  *(float4*)(out + (size_t)n*DMODEL + c0 + 4) = o1;
}

// ---------------- launcher ----------------
extern "C" void kernel_launch(void* const* d_in, const int* in_sizes, int n_in,
                              void* d_out, int out_size, void* d_ws, size_t ws_size,
                              hipStream_t stream) {
  const float* x     = (const float*)d_in[0];
  const float* W_up  = (const float*)d_in[1];
  const float* W_gt  = (const float*)d_in[2];
  const float* W_dn  = (const float*)d_in[3];
  const float* g_in  = (const float*)d_in[4];
  float* out = (float*)d_out;
  char* ws = (char*)d_ws;

  int*   counts = (int*)(ws + O_COUNTS);
  int*   basep  = (int*)(ws + O_BASE);
  int*   cursor = (int*)(ws + O_CURSOR);
  int*   chtab  = (int*)(ws + O_CHT);
  int*   topi   = (int*)(ws + O_TOPI);
  float* topw   = (float*)(ws + O_TOPW);
  int*   tok    = (int*)(ws + O_TOK);
  float* wgt    = (float*)(ws + O_WGT);
  int*   slotnk = (int*)(ws + O_SLOTNK);
  unsigned short* xg    = (unsigned short*)(ws + O_XG);
  unsigned short* hbuf  = (unsigned short*)(ws + O_HBUF);
  unsigned short* ypart = xg;   // alias: xg dead after k_upgate

  k_zero   <<<1, 64, 0, stream>>>(counts, cursor);
  k_gate   <<<NTOK, 256, 0, stream>>>(x, g_in, topi, topw, counts);
  k_prefix <<<1, 64, 0, stream>>>(counts, basep, chtab);
  k_scatter<<<4, 256, 0, stream>>>(topi, topw, basep, cursor, tok, wgt, slotnk);
  k_gather <<<NSLOT, 256, 0, stream>>>(x, tok, xg);
  k_upgate <<<NCHMAX*HT_TILES, 256, 0, stream>>>(xg, W_up, W_gt, counts, basep, chtab, wgt, hbuf);
  k_down   <<<NCHMAX*CT_TILES, 256, 0, stream>>>(hbuf, W_dn, counts, basep, chtab, ypart);
  k_combine<<<NTOK, 256, 0, stream>>>(ypart, slotnk, out);
}